// Round 18
// baseline (140.321 us; speedup 1.0000x reference)
//
#include <hip/hip_runtime.h>

typedef float f32x4 __attribute__((ext_vector_type(4)));
typedef short s16x8 __attribute__((ext_vector_type(8)));
typedef unsigned int u32;
typedef u32 u32x4 __attribute__((ext_vector_type(4)));
typedef unsigned long long u64;
typedef unsigned short ush;

#define CD    256
#define NB    64
#define NBETA 512
#define NHID  512
#define PPB   32    // positions per fused block

__device__ __forceinline__ ush f2bf(float x) {
    u32 u = __builtin_bit_cast(u32, x);
    u += 0x7fffu + ((u >> 16) & 1u);
    return (ush)(u >> 16);
}
__device__ __forceinline__ float bf2f(ush h) {
    u32 u = ((u32)h) << 16;
    return __builtin_bit_cast(float, u);
}
__device__ __forceinline__ u32 cvtpk(float lo, float hi) {
    u32 r;
    asm("v_cvt_pk_bf16_f32 %0, %1, %2" : "=v"(r) : "v"(lo), "v"(hi));
    return r;
}
__device__ __forceinline__ float fexp2(float x) {  // 2^x
    float r;
    asm("v_exp_f32 %0, %1" : "=v"(r) : "v"(x));
    return r;
}

// ---------------------------------------------------------------------------
// Prep (proven): hws[b][beta] = h_t[b]·W_h_w[beta] + W_h_b + W_b (bf16);
//                wwb = bf16(W_w) [512][256].
// ---------------------------------------------------------------------------
__global__ __launch_bounds__(512) void prep_kernel(
    const float* __restrict__ h_t, const float* __restrict__ W_h_w,
    const float* __restrict__ W_h_b, const float* __restrict__ W_w,
    const float* __restrict__ W_b,
    ush* __restrict__ hws, ush* __restrict__ wwb)
{
    const int blk = blockIdx.x;
    const int tid = threadIdx.x;
    if (blk < NB) {
        __shared__ float hrow[NHID];
        hrow[tid] = h_t[blk * NHID + tid];
        __syncthreads();
        const float* wr = W_h_w + tid * NHID;
        float a0 = 0.f, a1 = 0.f, a2 = 0.f, a3 = 0.f;
        #pragma unroll 4
        for (int h = 0; h < NHID; h += 4) {
            f32x4 wv = *(const f32x4*)(wr + h);
            a0 = fmaf(wv.x, hrow[h], a0);
            a1 = fmaf(wv.y, hrow[h + 1], a1);
            a2 = fmaf(wv.z, hrow[h + 2], a2);
            a3 = fmaf(wv.w, hrow[h + 3], a3);
        }
        float acc = (a0 + a1) + (a2 + a3) + W_h_b[tid] + W_b[tid];
        hws[blk * NBETA + tid] = f2bf(acc);   // [b][beta]
    } else {
        const int idx = ((blk - NB) * 512 + tid) * 8;
        f32x4 a = *(const f32x4*)(W_w + idx);
        f32x4 b = *(const f32x4*)(W_w + idx + 4);
        s16x8 pk;
        pk[0] = (short)f2bf(a.x); pk[1] = (short)f2bf(a.y);
        pk[2] = (short)f2bf(a.z); pk[3] = (short)f2bf(a.w);
        pk[4] = (short)f2bf(b.x); pk[5] = (short)f2bf(b.y);
        pk[6] = (short)f2bf(b.z); pk[7] = (short)f2bf(b.w);
        *(s16x8*)(wwb + idx) = pk;
    }
}

// ---------------------------------------------------------------------------
// Fused: r17 skeleton (8 waves x 64 betas, A in regs, 3-buffer Vt, prefetch
// dist 2, ONE barrier/pos, raw-partial ewP, setprio K-chains) + round-18:
//   (a) DEFERRED WSUM: pos i's e-sum/wsum runs in iteration i+1's body,
//       in the same straight-line region as the K-chain MFMAs (the loop
//       back-edge previously blocked this interleave — r17's lesson).
//       Hazards: ewP parity & Vt slot reads all separated from their next
//       writers by >=1 barrier (audit in comments).
//   (b) pe dep-chain split: 2 independent 8-deep fmaf partials per pe.
// ---------------------------------------------------------------------------
__global__ __launch_bounds__(512, 2) void fused(
    const float* __restrict__ V,
    const ush* __restrict__ wwb,
    const ush* __restrict__ hws,
    const float* __restrict__ beta_w,
    const float* __restrict__ beta_b,
    float* __restrict__ num,
    float* __restrict__ lsum)
{
    __shared__ __align__(16) char VtB[3][16384];     // [32 b][256 c] bf16 swz
    __shared__ float nbS[NBETA];                     // -2*beta_w
    __shared__ __align__(16) float ewP[2][8][2][16][4]; // [par][w][n][r][g]

    const int tid = threadIdx.x;
    const int l = tid & 63, w = tid >> 6, g = l >> 4, r = l & 15;
    const int bl = tid & 31, cs = tid >> 5;        // b-lane, c-slice of 16
    const int bh = blockIdx.x & 1, chunk = blockIdx.x >> 1;

    nbS[tid] = -2.f * beta_w[tid];
    const float bbias = beta_b[0];

    float base = 0.f;
    #pragma unroll
    for (int m = 0; m < 4; ++m) {
        f32x4 t = *(const f32x4*)(beta_w + w * 64 + m * 16 + g * 4);
        base += (t.x + t.y) + (t.z + t.w);
    }

    // permanent A fragments: beta = w*64 + m*16 + r  (128 regs)
    const ush* wbase = wwb + (size_t)(w * 64 + r) * CD + g * 8;
    s16x8 a[4][8];
    #pragma unroll
    for (int m = 0; m < 4; ++m)
        #pragma unroll
        for (int ks = 0; ks < 8; ++ks)
            a[m][ks] = *(const s16x8*)(wbase + m * (16 * CD) + ks * 32);

    // permanent hterm: ua[m][n] = betas (w*64+m*16+g*4..+3) at b=bh*32+n*16+r
    const ush* hbase = hws + (size_t)(bh * 32 + r) * NBETA + w * 64 + g * 4;
    u64 ua[4][2];
    #pragma unroll
    for (int m = 0; m < 4; ++m)
        #pragma unroll
        for (int n = 0; n < 2; ++n)
            ua[m][n] = *(const u64*)(hbase + n * (16 * NBETA) + m * 16);

    const int p0 = chunk * PPB;
    const float* vbase = V + (size_t)p0 * (CD * NB) + bh * 32 + bl;
    const int wswz = (bl & 15) << 4;   // staging/wsum swizzle (row fn)
    const int rswz = r << 4;           // K-loop read swizzle (same row fn)

    float cacc[16];
    #pragma unroll
    for (int j = 0; j < 16; ++j) cacc[j] = 0.f;
    float lacc = 0.f;

    float nv[16];

    // deferred-wsum: e-sum over ewP[PAR] + weighted accumulate from slot SLOT
#define WSUM(PAR, SLOT)                                                       \
    {                                                                         \
        const int n_ = bl >> 4, r_ = bl & 15;                                 \
        float e = bbias;                                                      \
        _Pragma("unroll")                                                     \
        for (int wv = 0; wv < 8; ++wv) {                                      \
            f32x4 t = *(const f32x4*)(&ewP[PAR][wv][n_][r_][0]);              \
            e += (t.x + t.y) + (t.z + t.w);                                   \
        }                                                                     \
        float wgt = __expf(e);                                                \
        lacc += wgt;                                                          \
        const char* vb = VtB[0] + (SLOT) + bl * 512;                          \
        _Pragma("unroll")                                                     \
        for (int k = 0; k < 2; ++k) {                                         \
            s16x8 v = *(const s16x8*)(vb + ((cs * 32 + k * 16) ^ wswz));      \
            _Pragma("unroll")                                                 \
            for (int j = 0; j < 8; ++j)                                       \
                cacc[k * 8 + j] = fmaf(wgt, bf2f((ush)v[j]), cacc[k * 8 + j]);\
        }                                                                     \
    }

    // prologue: stage pos0 -> buf0; issue pos1 loads into nv
    {
        #pragma unroll
        for (int j = 0; j < 16; ++j)
            nv[j] = __builtin_nontemporal_load(vbase + (cs * 16 + j) * NB);
        char* db = VtB[0] + bl * 512;
        u32x4 pk0 = {cvtpk(nv[0], nv[1]), cvtpk(nv[2], nv[3]),
                     cvtpk(nv[4], nv[5]), cvtpk(nv[6], nv[7])};
        *(u32x4*)(db + ((cs * 32) ^ wswz)) = pk0;
        u32x4 pk1 = {cvtpk(nv[8], nv[9]), cvtpk(nv[10], nv[11]),
                     cvtpk(nv[12], nv[13]), cvtpk(nv[14], nv[15])};
        *(u32x4*)(db + ((cs * 32 + 16) ^ wswz)) = pk1;
    }
    {
        const float* vp = vbase + (size_t)(CD * NB);
        #pragma unroll
        for (int j = 0; j < 16; ++j)
            nv[j] = __builtin_nontemporal_load(vp + (cs * 16 + j) * NB);
    }
    __syncthreads();

    int prv = 32768;            // slot of pos i-1 (valid from i>=1)
    int cur = 0, nxt = 16384;
    for (int i = 0; i < PPB; ++i) {
        const char* vt = VtB[0] + cur;

        // (1) stage pos i+1 (loads issued LAST iteration)
        if (i + 1 < PPB) {
            char* db = VtB[0] + nxt + bl * 512;
            u32x4 pk0 = {cvtpk(nv[0], nv[1]), cvtpk(nv[2], nv[3]),
                         cvtpk(nv[4], nv[5]), cvtpk(nv[6], nv[7])};
            *(u32x4*)(db + ((cs * 32) ^ wswz)) = pk0;
            u32x4 pk1 = {cvtpk(nv[8], nv[9]), cvtpk(nv[10], nv[11]),
                         cvtpk(nv[12], nv[13]), cvtpk(nv[14], nv[15])};
            *(u32x4*)(db + ((cs * 32 + 16) ^ wswz)) = pk1;
        }
        // (2) issue pos i+2 loads
        if (i + 2 < PPB) {
            const float* vp = vbase + (size_t)(i + 2) * (CD * NB);
            #pragma unroll
            for (int j = 0; j < 16; ++j)
                nv[j] = __builtin_nontemporal_load(vp + (cs * 16 + j) * NB);
        }

        // (3) DEFERRED wsum for pos i-1 — same straight-line region as the
        // K-chains below; compiler interleaves its VALU/LDS-reads under the
        // MFMA latency. ewP[(i-1)&1] next written at iter i+1 (barrier(i)
        // between); Vt slot prv next staged at iter i+2 (barrier(i+1)).
        if (i > 0) WSUM((i - 1) & 1, prv)

        const char* vrow = vt + r * 512;

        // (4) n=0: init from ua, K-chain (setprio), epilogue (split chains)
        f32x4 acc0[4];
        #pragma unroll
        for (int m = 0; m < 4; ++m) {
            u64 h = ua[m][0];
            acc0[m] = (f32x4){bf2f((ush)h), bf2f((ush)(h >> 16)),
                              bf2f((ush)(h >> 32)), bf2f((ush)(h >> 48))};
        }
        __builtin_amdgcn_s_setprio(1);
        #pragma unroll
        for (int ks = 0; ks < 8; ++ks) {
            const int off = ((ks << 6) | (g << 4)) ^ rswz;
            s16x8 b0 = *(const s16x8*)(vrow + off);
            #pragma unroll
            for (int m = 0; m < 4; ++m)
                acc0[m] = __builtin_amdgcn_mfma_f32_16x16x32_bf16(a[m][ks], b0, acc0[m], 0, 0, 0);
        }
        __builtin_amdgcn_s_setprio(0);
        {
            float peA = 0.f, peB = 0.f;
            #pragma unroll
            for (int m = 0; m < 4; ++m) {
                f32x4 nbv = *(const f32x4*)(&nbS[w * 64 + m * 16 + g * 4]);
                #pragma unroll
                for (int q = 0; q < 4; ++q) {
                    float s = __builtin_amdgcn_rcpf(
                        1.f + fexp2(acc0[m][q] * 2.8853900817779268f));
                    if (m < 2) peA = fmaf(nbv[q], s, peA);
                    else       peB = fmaf(nbv[q], s, peB);
                }
            }
            ewP[i & 1][w][0][r][g] = base + peA + peB;
        }

        // (5) n=1: init, K-chain, epilogue
        f32x4 acc1[4];
        #pragma unroll
        for (int m = 0; m < 4; ++m) {
            u64 h = ua[m][1];
            acc1[m] = (f32x4){bf2f((ush)h), bf2f((ush)(h >> 16)),
                              bf2f((ush)(h >> 32)), bf2f((ush)(h >> 48))};
        }
        __builtin_amdgcn_s_setprio(1);
        #pragma unroll
        for (int ks = 0; ks < 8; ++ks) {
            const int off = ((ks << 6) | (g << 4)) ^ rswz;
            s16x8 b1 = *(const s16x8*)(vrow + 8192 + off);
            #pragma unroll
            for (int m = 0; m < 4; ++m)
                acc1[m] = __builtin_amdgcn_mfma_f32_16x16x32_bf16(a[m][ks], b1, acc1[m], 0, 0, 0);
        }
        __builtin_amdgcn_s_setprio(0);
        {
            float peA = 0.f, peB = 0.f;
            #pragma unroll
            for (int m = 0; m < 4; ++m) {
                f32x4 nbv = *(const f32x4*)(&nbS[w * 64 + m * 16 + g * 4]);
                #pragma unroll
                for (int q = 0; q < 4; ++q) {
                    float s = __builtin_amdgcn_rcpf(
                        1.f + fexp2(acc1[m][q] * 2.8853900817779268f));
                    if (m < 2) peA = fmaf(nbv[q], s, peA);
                    else       peB = fmaf(nbv[q], s, peB);
                }
            }
            ewP[i & 1][w][1][r][g] = base + peA + peB;
        }

        __syncthreads();   // the ONLY barrier per position

        prv = cur;
        cur = nxt;
        nxt += 16384;
        if (nxt == 49152) nxt = 0;
    }

    // final deferred wsum: pos PPB-1 (parity (PPB-1)&1, slot prv)
    WSUM((PPB - 1) & 1, prv)

#undef WSUM

    // partials: num[block][32 b][256 c]
    float* np = num + (size_t)blockIdx.x * (32 * CD) + bl * CD + cs * 16;
    #pragma unroll
    for (int k = 0; k < 4; ++k)
        *(f32x4*)(np + k * 4) =
            (f32x4){cacc[k * 4], cacc[k * 4 + 1], cacc[k * 4 + 2], cacc[k * 4 + 3]};
    if (cs == 0) lsum[blockIdx.x * 32 + bl] = lacc;
}

// ---------------------------------------------------------------------------
// Combine: 256 blocks = (b 64 x cq 4); 256 thr = (cl 64 x kq 4).
// ---------------------------------------------------------------------------
__global__ __launch_bounds__(256) void combine4(
    const float* __restrict__ num, const float* __restrict__ lsum,
    float* __restrict__ out)
{
    __shared__ float rs[4][64];
    __shared__ float rl[4][64];
    const int b = blockIdx.x >> 2, cq = blockIdx.x & 3;
    const int bh = b >> 5, blr = b & 31;
    const int cl = threadIdx.x & 63, kq = threadIdx.x >> 6;

    float s = 0.f, ls = 0.f;
    #pragma unroll 4
    for (int ch = kq * 32; ch < kq * 32 + 32; ++ch) {
        const int blk = ch * 2 + bh;
        s += num[(size_t)blk * (32 * CD) + blr * CD + cq * 64 + cl];
        ls += lsum[blk * 32 + blr];
    }
    rs[kq][cl] = s; rl[kq][cl] = ls;
    __syncthreads();
    if (kq == 0) {
        float sn = rs[0][cl] + rs[1][cl] + rs[2][cl] + rs[3][cl];
        float sl = rl[0][cl] + rl[1][cl] + rl[2][cl] + rl[3][cl];
        out[b * CD + cq * 64 + cl] = sn / sl;
    }
}

extern "C" void kernel_launch(void* const* d_in, const int* in_sizes, int n_in,
                              void* d_out, int out_size, void* d_ws, size_t ws_size,
                              hipStream_t stream)
{
    (void)in_sizes; (void)n_in; (void)out_size; (void)ws_size;
    const float* V      = (const float*)d_in[0];
    const float* h_t    = (const float*)d_in[1];
    const float* W_h_w  = (const float*)d_in[2];
    const float* W_h_b  = (const float*)d_in[3];
    const float* W_w    = (const float*)d_in[4];
    const float* W_b    = (const float*)d_in[5];
    const float* beta_w = (const float*)d_in[6];
    const float* beta_b = (const float*)d_in[7];

    char* ws = (char*)d_ws;
    ush*   wwb = (ush*)ws;                                   // 256 KB
    ush*   hws = (ush*)(ws + 262144);                        // 64 KB
    float* num = (float*)(ws + 262144 + 65536);              // 8.4 MB
    float* lsm = (float*)(ws + 262144 + 65536 + 8388608);    // 32 KB

    hipLaunchKernelGGL(prep_kernel, dim3(96), dim3(512), 0, stream,
                       h_t, W_h_w, W_h_b, W_w, W_b, hws, wwb);
    hipLaunchKernelGGL(fused, dim3(256), dim3(512), 0, stream,
                       V, wwb, hws, beta_w, beta_b, num, lsm);
    hipLaunchKernelGGL(combine4, dim3(256), dim3(256), 0, stream,
                       num, lsm, (float*)d_out);
}

// Round 19
// 138.693 us; speedup vs baseline: 1.0117x; 1.0117x over previous
//
#include <hip/hip_runtime.h>

typedef float f32x4 __attribute__((ext_vector_type(4)));
typedef short s16x8 __attribute__((ext_vector_type(8)));
typedef unsigned int u32;
typedef u32 u32x4 __attribute__((ext_vector_type(4)));
typedef unsigned long long u64;
typedef unsigned short ush;

#define CD    256
#define NB    64
#define NBETA 512
#define NHID  512
#define PPB   32    // positions per fused block

__device__ __forceinline__ ush f2bf(float x) {
    u32 u = __builtin_bit_cast(u32, x);
    u += 0x7fffu + ((u >> 16) & 1u);
    return (ush)(u >> 16);
}
__device__ __forceinline__ float bf2f(ush h) {
    u32 u = ((u32)h) << 16;
    return __builtin_bit_cast(float, u);
}
__device__ __forceinline__ u32 cvtpk(float lo, float hi) {
    u32 r;
    asm("v_cvt_pk_bf16_f32 %0, %1, %2" : "=v"(r) : "v"(lo), "v"(hi));
    return r;
}
__device__ __forceinline__ float fexp2(float x) {  // 2^x
    float r;
    asm("v_exp_f32 %0, %1" : "=v"(r) : "v"(x));
    return r;
}

// ---------------------------------------------------------------------------
// Prep (proven): hws[b][beta] = h_t[b]·W_h_w[beta] + W_h_b + W_b (bf16);
//                wwb = bf16(W_w) [512][256].
// ---------------------------------------------------------------------------
__global__ __launch_bounds__(512) void prep_kernel(
    const float* __restrict__ h_t, const float* __restrict__ W_h_w,
    const float* __restrict__ W_h_b, const float* __restrict__ W_w,
    const float* __restrict__ W_b,
    ush* __restrict__ hws, ush* __restrict__ wwb)
{
    const int blk = blockIdx.x;
    const int tid = threadIdx.x;
    if (blk < NB) {
        __shared__ float hrow[NHID];
        hrow[tid] = h_t[blk * NHID + tid];
        __syncthreads();
        const float* wr = W_h_w + tid * NHID;
        float a0 = 0.f, a1 = 0.f, a2 = 0.f, a3 = 0.f;
        #pragma unroll 4
        for (int h = 0; h < NHID; h += 4) {
            f32x4 wv = *(const f32x4*)(wr + h);
            a0 = fmaf(wv.x, hrow[h], a0);
            a1 = fmaf(wv.y, hrow[h + 1], a1);
            a2 = fmaf(wv.z, hrow[h + 2], a2);
            a3 = fmaf(wv.w, hrow[h + 3], a3);
        }
        float acc = (a0 + a1) + (a2 + a3) + W_h_b[tid] + W_b[tid];
        hws[blk * NBETA + tid] = f2bf(acc);   // [b][beta]
    } else {
        const int idx = ((blk - NB) * 512 + tid) * 8;
        f32x4 a = *(const f32x4*)(W_w + idx);
        f32x4 b = *(const f32x4*)(W_w + idx + 4);
        s16x8 pk;
        pk[0] = (short)f2bf(a.x); pk[1] = (short)f2bf(a.y);
        pk[2] = (short)f2bf(a.z); pk[3] = (short)f2bf(a.w);
        pk[4] = (short)f2bf(b.x); pk[5] = (short)f2bf(b.y);
        pk[6] = (short)f2bf(b.z); pk[7] = (short)f2bf(b.w);
        *(s16x8*)(wwb + idx) = pk;
    }
}

// ---------------------------------------------------------------------------
// Fused (FINAL, round-17 measured best: 139.3 us total):
// 512 thr = 8 waves x 64 betas, block = (b-half, 32 positions).
// V read from HBM exactly once; single pass.
//   - W_w A-fragments permanent in unified regs (a[4][8] = 128)
//   - hterm permanent in regs (ua[4][2] = 8)
//   - 3-buffer Vt rotation, prefetch distance 2, ONE barrier per position
//   - full-range (bl&15) XOR swizzle: conflict-free b128 on all LDS paths
//   - raw-partial ewP[par][w][n][r][g]: NO shfl_xor chains pre-barrier
//     (the r17 win: -12.5 us); g-sum folds into post-barrier e-sum
//   - s_setprio(1) around MFMA K-chains (T5)
// Ledger: TLP x2 null (r12), barrier/2 null (r14/r18-defer), dual-acc
// overlap spill (r15), wsum-in-reg worse (r10) => this is the source-level
// optimum of this structure; residual is phase serialization (~9K cyc/pos
// vs ~3K max-pipe) addressable only below HIP source level.
// ---------------------------------------------------------------------------
__global__ __launch_bounds__(512, 2) void fused(
    const float* __restrict__ V,
    const ush* __restrict__ wwb,
    const ush* __restrict__ hws,
    const float* __restrict__ beta_w,
    const float* __restrict__ beta_b,
    float* __restrict__ num,
    float* __restrict__ lsum)
{
    __shared__ __align__(16) char VtB[3][16384];     // [32 b][256 c] bf16 swz
    __shared__ float nbS[NBETA];                     // -2*beta_w
    __shared__ __align__(16) float ewP[2][8][2][16][4]; // [par][w][n][r][g]

    const int tid = threadIdx.x;
    const int l = tid & 63, w = tid >> 6, g = l >> 4, r = l & 15;
    const int bl = tid & 31, cs = tid >> 5;        // b-lane, c-slice of 16
    const int bh = blockIdx.x & 1, chunk = blockIdx.x >> 1;

    nbS[tid] = -2.f * beta_w[tid];
    const float bbias = beta_b[0];

    float base = 0.f;
    #pragma unroll
    for (int m = 0; m < 4; ++m) {
        f32x4 t = *(const f32x4*)(beta_w + w * 64 + m * 16 + g * 4);
        base += (t.x + t.y) + (t.z + t.w);
    }

    // permanent A fragments: beta = w*64 + m*16 + r  (128 regs)
    const ush* wbase = wwb + (size_t)(w * 64 + r) * CD + g * 8;
    s16x8 a[4][8];
    #pragma unroll
    for (int m = 0; m < 4; ++m)
        #pragma unroll
        for (int ks = 0; ks < 8; ++ks)
            a[m][ks] = *(const s16x8*)(wbase + m * (16 * CD) + ks * 32);

    // permanent hterm: ua[m][n] = betas (w*64+m*16+g*4..+3) at b=bh*32+n*16+r
    const ush* hbase = hws + (size_t)(bh * 32 + r) * NBETA + w * 64 + g * 4;
    u64 ua[4][2];
    #pragma unroll
    for (int m = 0; m < 4; ++m)
        #pragma unroll
        for (int n = 0; n < 2; ++n)
            ua[m][n] = *(const u64*)(hbase + n * (16 * NBETA) + m * 16);

    const int p0 = chunk * PPB;
    const float* vbase = V + (size_t)p0 * (CD * NB) + bh * 32 + bl;
    const int wswz = (bl & 15) << 4;   // staging/wsum swizzle (row fn)
    const int rswz = r << 4;           // K-loop read swizzle (same row fn)

    float cacc[16];
    #pragma unroll
    for (int j = 0; j < 16; ++j) cacc[j] = 0.f;
    float lacc = 0.f;

    float nv[16];

    // prologue: stage pos0 -> buf0; issue pos1 loads into nv
    {
        #pragma unroll
        for (int j = 0; j < 16; ++j)
            nv[j] = __builtin_nontemporal_load(vbase + (cs * 16 + j) * NB);
        char* db = VtB[0] + bl * 512;
        u32x4 pk0 = {cvtpk(nv[0], nv[1]), cvtpk(nv[2], nv[3]),
                     cvtpk(nv[4], nv[5]), cvtpk(nv[6], nv[7])};
        *(u32x4*)(db + ((cs * 32) ^ wswz)) = pk0;
        u32x4 pk1 = {cvtpk(nv[8], nv[9]), cvtpk(nv[10], nv[11]),
                     cvtpk(nv[12], nv[13]), cvtpk(nv[14], nv[15])};
        *(u32x4*)(db + ((cs * 32 + 16) ^ wswz)) = pk1;
    }
    {
        const float* vp = vbase + (size_t)(CD * NB);
        #pragma unroll
        for (int j = 0; j < 16; ++j)
            nv[j] = __builtin_nontemporal_load(vp + (cs * 16 + j) * NB);
    }
    __syncthreads();

    int cur = 0, nxt = 16384;
    for (int i = 0; i < PPB; ++i) {
        const char* vt = VtB[0] + cur;

        // (1) stage pos i+1 (loads issued LAST iteration)
        if (i + 1 < PPB) {
            char* db = VtB[0] + nxt + bl * 512;
            u32x4 pk0 = {cvtpk(nv[0], nv[1]), cvtpk(nv[2], nv[3]),
                         cvtpk(nv[4], nv[5]), cvtpk(nv[6], nv[7])};
            *(u32x4*)(db + ((cs * 32) ^ wswz)) = pk0;
            u32x4 pk1 = {cvtpk(nv[8], nv[9]), cvtpk(nv[10], nv[11]),
                         cvtpk(nv[12], nv[13]), cvtpk(nv[14], nv[15])};
            *(u32x4*)(db + ((cs * 32 + 16) ^ wswz)) = pk1;
        }
        // (2) issue pos i+2 loads
        if (i + 2 < PPB) {
            const float* vp = vbase + (size_t)(i + 2) * (CD * NB);
            #pragma unroll
            for (int j = 0; j < 16; ++j)
                nv[j] = __builtin_nontemporal_load(vp + (cs * 16 + j) * NB);
        }

        const char* vrow = vt + r * 512;

        // (3) n=0: init from ua, K-chain (setprio-wrapped), epilogue
        f32x4 acc0[4];
        #pragma unroll
        for (int m = 0; m < 4; ++m) {
            u64 h = ua[m][0];
            acc0[m] = (f32x4){bf2f((ush)h), bf2f((ush)(h >> 16)),
                              bf2f((ush)(h >> 32)), bf2f((ush)(h >> 48))};
        }
        __builtin_amdgcn_s_setprio(1);
        #pragma unroll
        for (int ks = 0; ks < 8; ++ks) {
            const int off = ((ks << 6) | (g << 4)) ^ rswz;
            s16x8 b0 = *(const s16x8*)(vrow + off);
            #pragma unroll
            for (int m = 0; m < 4; ++m)
                acc0[m] = __builtin_amdgcn_mfma_f32_16x16x32_bf16(a[m][ks], b0, acc0[m], 0, 0, 0);
        }
        __builtin_amdgcn_s_setprio(0);
        float pe0 = base;
        #pragma unroll
        for (int m = 0; m < 4; ++m) {
            f32x4 nbv = *(const f32x4*)(&nbS[w * 64 + m * 16 + g * 4]);
            #pragma unroll
            for (int q = 0; q < 4; ++q) {
                float s = __builtin_amdgcn_rcpf(
                    1.f + fexp2(acc0[m][q] * 2.8853900817779268f));
                pe0 = fmaf(nbv[q], s, pe0);
            }
        }

        // (4) n=1: init, K-chain, epilogue
        f32x4 acc1[4];
        #pragma unroll
        for (int m = 0; m < 4; ++m) {
            u64 h = ua[m][1];
            acc1[m] = (f32x4){bf2f((ush)h), bf2f((ush)(h >> 16)),
                              bf2f((ush)(h >> 32)), bf2f((ush)(h >> 48))};
        }
        __builtin_amdgcn_s_setprio(1);
        #pragma unroll
        for (int ks = 0; ks < 8; ++ks) {
            const int off = ((ks << 6) | (g << 4)) ^ rswz;
            s16x8 b1 = *(const s16x8*)(vrow + 8192 + off);
            #pragma unroll
            for (int m = 0; m < 4; ++m)
                acc1[m] = __builtin_amdgcn_mfma_f32_16x16x32_bf16(a[m][ks], b1, acc1[m], 0, 0, 0);
        }
        __builtin_amdgcn_s_setprio(0);
        float pe1 = base;
        #pragma unroll
        for (int m = 0; m < 4; ++m) {
            f32x4 nbv = *(const f32x4*)(&nbS[w * 64 + m * 16 + g * 4]);
            #pragma unroll
            for (int q = 0; q < 4; ++q) {
                float s = __builtin_amdgcn_rcpf(
                    1.f + fexp2(acc1[m][q] * 2.8853900817779268f));
                pe1 = fmaf(nbv[q], s, pe1);
            }
        }

        // (5) NO shfl chains: every lane writes its raw partial.
        // Per-wave write addrs r*4+g = 64 consecutive words: conflict-free.
        ewP[i & 1][w][0][r][g] = pe0;
        ewP[i & 1][w][1][r][g] = pe1;

        __syncthreads();   // the ONLY barrier per position

        // (6) e-sum (8x b128 over [w][n][r][0..3]) + wsum from staged tile
        {
            const int n_ = bl >> 4, r_ = bl & 15;
            float e = bbias;
            #pragma unroll
            for (int wv = 0; wv < 8; ++wv) {
                f32x4 t = *(const f32x4*)(&ewP[i & 1][wv][n_][r_][0]);
                e += (t.x + t.y) + (t.z + t.w);
            }
            float wgt = __expf(e);
            lacc += wgt;
            const char* vb = vt + bl * 512;
            #pragma unroll
            for (int k = 0; k < 2; ++k) {
                s16x8 v = *(const s16x8*)(vb + ((cs * 32 + k * 16) ^ wswz));
                #pragma unroll
                for (int j = 0; j < 8; ++j)
                    cacc[k * 8 + j] = fmaf(wgt, bf2f((ush)v[j]), cacc[k * 8 + j]);
            }
        }

        cur = nxt;
        nxt += 16384;
        if (nxt == 49152) nxt = 0;
    }

    // partials: num[block][32 b][256 c]
    float* np = num + (size_t)blockIdx.x * (32 * CD) + bl * CD + cs * 16;
    #pragma unroll
    for (int k = 0; k < 4; ++k)
        *(f32x4*)(np + k * 4) =
            (f32x4){cacc[k * 4], cacc[k * 4 + 1], cacc[k * 4 + 2], cacc[k * 4 + 3]};
    if (cs == 0) lsum[blockIdx.x * 32 + bl] = lacc;
}

// ---------------------------------------------------------------------------
// Combine: 256 blocks = (b 64 x cq 4); 256 thr = (cl 64 x kq 4).
// ---------------------------------------------------------------------------
__global__ __launch_bounds__(256) void combine4(
    const float* __restrict__ num, const float* __restrict__ lsum,
    float* __restrict__ out)
{
    __shared__ float rs[4][64];
    __shared__ float rl[4][64];
    const int b = blockIdx.x >> 2, cq = blockIdx.x & 3;
    const int bh = b >> 5, blr = b & 31;
    const int cl = threadIdx.x & 63, kq = threadIdx.x >> 6;

    float s = 0.f, ls = 0.f;
    #pragma unroll 4
    for (int ch = kq * 32; ch < kq * 32 + 32; ++ch) {
        const int blk = ch * 2 + bh;
        s += num[(size_t)blk * (32 * CD) + blr * CD + cq * 64 + cl];
        ls += lsum[blk * 32 + blr];
    }
    rs[kq][cl] = s; rl[kq][cl] = ls;
    __syncthreads();
    if (kq == 0) {
        float sn = rs[0][cl] + rs[1][cl] + rs[2][cl] + rs[3][cl];
        float sl = rl[0][cl] + rl[1][cl] + rl[2][cl] + rl[3][cl];
        out[b * CD + cq * 64 + cl] = sn / sl;
    }
}

extern "C" void kernel_launch(void* const* d_in, const int* in_sizes, int n_in,
                              void* d_out, int out_size, void* d_ws, size_t ws_size,
                              hipStream_t stream)
{
    (void)in_sizes; (void)n_in; (void)out_size; (void)ws_size;
    const float* V      = (const float*)d_in[0];
    const float* h_t    = (const float*)d_in[1];
    const float* W_h_w  = (const float*)d_in[2];
    const float* W_h_b  = (const float*)d_in[3];
    const float* W_w    = (const float*)d_in[4];
    const float* W_b    = (const float*)d_in[5];
    const float* beta_w = (const float*)d_in[6];
    const float* beta_b = (const float*)d_in[7];

    char* ws = (char*)d_ws;
    ush*   wwb = (ush*)ws;                                   // 256 KB
    ush*   hws = (ush*)(ws + 262144);                        // 64 KB
    float* num = (float*)(ws + 262144 + 65536);              // 8.4 MB
    float* lsm = (float*)(ws + 262144 + 65536 + 8388608);    // 32 KB

    hipLaunchKernelGGL(prep_kernel, dim3(96), dim3(512), 0, stream,
                       h_t, W_h_w, W_h_b, W_w, W_b, hws, wwb);
    hipLaunchKernelGGL(fused, dim3(256), dim3(512), 0, stream,
                       V, wwb, hws, beta_w, beta_b, num, lsm);
    hipLaunchKernelGGL(combine4, dim3(256), dim3(256), 0, stream,
                       num, lsm, (float*)d_out);
}